// Round 3
// baseline (57634.222 us; speedup 1.0000x reference)
//
#include <hip/hip_runtime.h>
#include <hip/hip_cooperative_groups.h>

namespace cg = cooperative_groups;

// L=2, B=64, T=256, I=H=1024, G=2048
// P chunk layout: [TS][B][G] (local row m = tL*64 + b)
// h layout: [B][H] natural (lane = b), double-buffered hA/hB, parity by global t

__device__ __forceinline__ float wave_sum(float v) {
#pragma unroll
  for (int m = 1; m < 64; m <<= 1) v += __shfl_xor(v, m, 64);
  return v;
}

// ---- input projection (bias dropped: BN cancels it): P[mL][n] = sum_k in[b][t0+tL][k]*w[n][k]
__global__ __launch_bounds__(256) void proj_gemm(
    const float* __restrict__ in, const float* __restrict__ w,
    float* __restrict__ P, int t0)
{
  __shared__ float As[8][132];
  __shared__ float Bs[8][132];
  const int tid = threadIdx.x;
  const int m0 = blockIdx.y << 7;      // local rows
  const int n0 = blockIdx.x << 7;
  const int tm = tid >> 4, tn = tid & 15;
  const int lr = tid >> 1;
  const int lk = (tid & 1) << 2;
  const int mA = m0 + lr;
  const int bb = mA & 63;
  const int tg = t0 + (mA >> 6);
  const float* arow = in + ((size_t)bb << 18) + ((size_t)tg << 10) + lk;
  const float* brow = w + ((size_t)(n0 + lr) << 10) + lk;
  float acc[2][2][4][4] = {};
  for (int k0 = 0; k0 < 1024; k0 += 8) {
    float4 av = *(const float4*)(arow + k0);
    float4 bv = *(const float4*)(brow + k0);
    __syncthreads();
    As[lk + 0][lr] = av.x; As[lk + 1][lr] = av.y; As[lk + 2][lr] = av.z; As[lk + 3][lr] = av.w;
    Bs[lk + 0][lr] = bv.x; Bs[lk + 1][lr] = bv.y; Bs[lk + 2][lr] = bv.z; Bs[lk + 3][lr] = bv.w;
    __syncthreads();
#pragma unroll
    for (int kk = 0; kk < 8; ++kk) {
      float4 a0 = *(const float4*)&As[kk][tm << 2];
      float4 a1 = *(const float4*)&As[kk][(tm << 2) + 64];
      float4 b0 = *(const float4*)&Bs[kk][tn << 2];
      float4 b1 = *(const float4*)&Bs[kk][(tn << 2) + 64];
      const float* ap0 = (const float*)&a0;
      const float* ap1 = (const float*)&a1;
      const float* bp0 = (const float*)&b0;
      const float* bp1 = (const float*)&b1;
#pragma unroll
      for (int i = 0; i < 4; ++i)
#pragma unroll
        for (int j = 0; j < 4; ++j) {
          acc[0][0][i][j] = fmaf(ap0[i], bp0[j], acc[0][0][i][j]);
          acc[0][1][i][j] = fmaf(ap0[i], bp1[j], acc[0][1][i][j]);
          acc[1][0][i][j] = fmaf(ap1[i], bp0[j], acc[1][0][i][j]);
          acc[1][1][i][j] = fmaf(ap1[i], bp1[j], acc[1][1][i][j]);
        }
    }
  }
#pragma unroll
  for (int mi = 0; mi < 2; ++mi)
#pragma unroll
    for (int i = 0; i < 4; ++i) {
      int m = m0 + (mi << 6) + (tm << 2) + i;
      float* prow = P + ((size_t)m << 11) + n0 + (tn << 2);
      *(float4*)prow        = make_float4(acc[mi][0][i][0], acc[mi][0][i][1], acc[mi][0][i][2], acc[mi][0][i][3]);
      *(float4*)(prow + 64) = make_float4(acc[mi][1][i][0], acc[mi][1][i][1], acc[mi][1][i][2], acc[mi][1][i][3]);
    }
}

// ---- per-(tL,g) BN stats of P -> scale/shift (in_part = P*sc + sh)
__global__ __launch_bounds__(256) void bn_stats(
    const float* __restrict__ P, const float* __restrict__ iw, const float* __restrict__ ib,
    float* __restrict__ sc, float* __restrict__ sh)
{
  const int t = blockIdx.y;                  // local
  const int g = (blockIdx.x << 8) + threadIdx.x;
  const float* col = P + (((size_t)t << 6) << 11) + g;
  float s = 0.f, q = 0.f;
#pragma unroll 8
  for (int b = 0; b < 64; ++b) { float v = col[(size_t)b << 11]; s += v; q = fmaf(v, v, q); }
  float m = s * 0.015625f;
  float var = fmaf(-m, m, q * 0.015625f);
  float scale = iw[g] * rsqrtf(var + 1e-5f);
  sc[(t << 11) + g] = scale;
  sh[(t << 11) + g] = fmaf(-m, scale, ib[g]);
}

// ---- persistent cooperative recurrence over TS steps (one grid.sync per step)
// 256 blocks x 512 threads. Wave = one gate column full-k: cs<4 -> u-col bid*4+cs,
// cs>=4 -> o-col bid*4+(cs-4)+1024. lane = batch b.
__global__ __launch_bounds__(512) void recur(
    const float* __restrict__ P, const float* __restrict__ sc, const float* __restrict__ sh,
    const float* __restrict__ whh, const float* __restrict__ hww, const float* __restrict__ hwb,
    const float* __restrict__ hx0, float* __restrict__ hA, float* __restrict__ hB,
    float* __restrict__ out, int t0, int TS)
{
  cg::grid_group grid = cg::this_grid();
  const int bid = blockIdx.x, tid = threadIdx.x;
  const int b = tid & 63, cs = tid >> 6;          // lane=batch, cs=col-slot 0..7
  const bool isU = (cs < 4);
  const int gcol = (bid << 2) + (cs & 3);         // 0..1023 (hidden index)
  const int g = isU ? gcol : (gcol + 1024);       // weight row / P col
  __shared__ float og_s[4][64];
  __shared__ float lout[64][5];                   // pad to break bank aliasing

  if (t0 == 0) {                                  // h0 = hx (layouts match: [B][H])
    int i = (bid << 9) + tid;
    if (i < 65536) hA[i] = hx0[i];
  }
  grid.sync();

  const float* wrow = whh + ((size_t)g << 10);
  const float wwv = hww[g];
  const float wbv = hwb[g];

  for (int tL = 0; tL < TS; ++tL) {
    const int t = t0 + tL;
    const float* hin = (t & 1) ? hB : hA;
    float*      hout = (t & 1) ? hA : hB;

    // prefetch step operands (latency hidden under the 1024-deep dot)
    const float pv  = P[(((size_t)(tL << 6) + b)) * 2048 + g];
    const float scv = sc[(tL << 11) + g];
    const float shv = sh[(tL << 11) + g];
    const float hold = hin[(b << 10) + gcol];

    const float* hrow = hin + (b << 10);
    float a0 = 0.f, a1 = 0.f, a2 = 0.f, a3 = 0.f;
    float a4 = 0.f, a5 = 0.f, a6 = 0.f, a7 = 0.f;
#pragma unroll 4
    for (int k0 = 0; k0 < 1024; k0 += 8) {
      float4 h0 = *(const float4*)(hrow + k0);
      float4 h1 = *(const float4*)(hrow + k0 + 4);
      float4 w0 = *(const float4*)(wrow + k0);
      float4 w1 = *(const float4*)(wrow + k0 + 4);
      a0 = fmaf(h0.x, w0.x, a0); a1 = fmaf(h0.y, w0.y, a1);
      a2 = fmaf(h0.z, w0.z, a2); a3 = fmaf(h0.w, w0.w, a3);
      a4 = fmaf(h1.x, w1.x, a4); a5 = fmaf(h1.y, w1.y, a5);
      a6 = fmaf(h1.z, w1.z, a6); a7 = fmaf(h1.w, w1.w, a7);
    }
    float d = ((a0 + a1) + (a2 + a3)) + ((a4 + a5) + (a6 + a7));

    // BN over batch (wave lanes)
    float s = wave_sum(d), q = wave_sum(d * d);
    float mu = s * 0.015625f;
    float var = fmaf(-mu, mu, q * 0.015625f);
    float hp = (d - mu) * (wwv * rsqrtf(var + 1e-5f)) + wbv;
    float gate = fmaf(pv, scv, shv) + hp;

    if (!isU) og_s[cs - 4][b] = fmaxf(gate, 0.f);
    __syncthreads();
    if (isU) {
      float ug = 1.f / (1.f + expf(-gate));
      float og = og_s[cs][b];
      float hnew = fmaf(ug, hold - og, og);       // ug*h + (1-ug)*og
      lout[b][cs] = hnew;
    }
    __syncthreads();
    if (tid < 64) {                               // one float4 per batch row
      float4 v = make_float4(lout[tid][0], lout[tid][1], lout[tid][2], lout[tid][3]);
      *(float4*)(hout + (tid << 10) + (bid << 2)) = v;
      *(float4*)(out + (((size_t)(tid << 8) + t) << 10) + (bid << 2)) = v;
    }
    grid.sync();
  }
}

extern "C" void kernel_launch(void* const* d_in, const int* in_sizes, int n_in,
                              void* d_out, int out_size, void* d_ws, size_t ws_size,
                              hipStream_t stream) {
  const float* x   = (const float*)d_in[0];
  const float* hx  = (const float*)d_in[1];
  const float* wih = (const float*)d_in[2];
  const float* whh = (const float*)d_in[3];
  // d_in[4], d_in[5] = b_ih, b_hh: cancelled exactly by batch-norm mean subtraction
  const float* biw = (const float*)d_in[6];
  const float* bib = (const float*)d_in[7];
  const float* bhw = (const float*)d_in[8];
  const float* bhb = (const float*)d_in[9];
  float* out = (float*)d_out;

  // ws floats: P TS*131072 | sc TS*2048 | sh TS*2048 | hA 65536 | hB 65536
  const size_t wsf = ws_size / 4;
  int TS = 256;
  while (TS > 2) {
    size_t need = (size_t)TS * 131072 + (size_t)TS * 4096 + 131072;
    if (need <= wsf) break;
    TS >>= 1;
  }
  float* P  = (float*)d_ws;
  float* sc = P + (size_t)TS * 131072;
  float* sh = sc + (size_t)TS * 2048;
  float* hA = sh + (size_t)TS * 2048;
  float* hB = hA + 65536;

  for (int layer = 0; layer < 2; ++layer) {
    const float* inp   = layer ? (const float*)out : x;
    const float* wih_l = wih + (size_t)layer * 2048 * 1024;
    const float* whh_l = whh + (size_t)layer * 2048 * 1024;
    const float* biw_l = biw + layer * 2048;
    const float* bib_l = bib + layer * 2048;
    const float* bhw_l = bhw + layer * 2048;
    const float* bhb_l = bhb + layer * 2048;
    const float* hx_l  = hx + (size_t)layer * 65536;

    for (int t0 = 0; t0 < 256; t0 += TS) {
      proj_gemm<<<dim3(16, TS / 2), 256, 0, stream>>>(inp, wih_l, P, t0);
      bn_stats<<<dim3(8, TS), 256, 0, stream>>>(P, biw_l, bib_l, sc, sh);
      int ts = TS;
      void* args[] = { (void*)&P, (void*)&sc, (void*)&sh, (void*)&whh_l, (void*)&bhw_l,
                       (void*)&bhb_l, (void*)&hx_l, (void*)&hA, (void*)&hB, (void*)&out,
                       (void*)&t0, (void*)&ts };
      hipLaunchCooperativeKernel((void*)recur, dim3(256), dim3(512), args, 0, stream);
    }
  }
}

// Round 6
// 13123.955 us; speedup vs baseline: 4.3915x; 4.3915x over previous
//
#include <hip/hip_runtime.h>
#include <hip/hip_bf16.h>

// L=2, B=64, T=256, I=H=1024, G=2048
// Split-precision bf16: X = X_hi + X_lo, each bf16; W*h = Whi*hhi + Whi*hlo + Wlo*hhi (f32 acc).
// P chunk: [TS][B][G] f32. h buffers: [B][H] bf16 hi/lo, double-buffered. w: [G][H] bf16 hi/lo.
// out: [B][T][H] f32 (also the f32 hold source for t>0).

typedef __attribute__((ext_vector_type(8))) short bf16x8;
typedef __attribute__((ext_vector_type(4))) float f32x4;

__device__ __forceinline__ float wave_sum(float v) {
#pragma unroll
  for (int m = 1; m < 64; m <<= 1) v += __shfl_xor(v, m, 64);
  return v;
}

__device__ __forceinline__ unsigned short f2bf(float f) {
  __hip_bfloat16 h = __float2bfloat16(f);
  return __builtin_bit_cast(unsigned short, h);
}
__device__ __forceinline__ float bf2f(unsigned short u) {
  unsigned int x = ((unsigned int)u) << 16;
  return __builtin_bit_cast(float, x);
}
__device__ __forceinline__ void split2(float v, unsigned short& hi, unsigned short& lo) {
  hi = f2bf(v);
  lo = f2bf(v - bf2f(hi));
}

// ---- convert whh (f32 [2048][1024]) -> bf16 hi/lo
__global__ __launch_bounds__(256) void wconv(
    const float* __restrict__ w, unsigned short* __restrict__ wh, unsigned short* __restrict__ wl)
{
  int i = ((blockIdx.x << 8) + threadIdx.x) << 3;
#pragma unroll
  for (int j = 0; j < 8; j += 4) {
    float4 a = *(const float4*)(w + i + j);
    ushort4 h, l;
    split2(a.x, h.x, l.x); split2(a.y, h.y, l.y);
    split2(a.z, h.z, l.z); split2(a.w, h.w, l.w);
    *(ushort4*)(wh + i + j) = h;
    *(ushort4*)(wl + i + j) = l;
  }
}

// ---- h0 = hx (f32 [B][H]) -> bf16 hi/lo [B][H]
__global__ __launch_bounds__(256) void hinit(
    const float* __restrict__ hx0, unsigned short* __restrict__ hh, unsigned short* __restrict__ hl)
{
  int i = ((blockIdx.x << 8) + threadIdx.x) << 3;
#pragma unroll
  for (int j = 0; j < 8; j += 4) {
    float4 a = *(const float4*)(hx0 + i + j);
    ushort4 h, l;
    split2(a.x, h.x, l.x); split2(a.y, h.y, l.y);
    split2(a.z, h.z, l.z); split2(a.w, h.w, l.w);
    *(ushort4*)(hh + i + j) = h;
    *(ushort4*)(hl + i + j) = l;
  }
}

// ---- input projection (bias dropped: BN cancels it): P[mL][n] = sum_k in[b][t0+tL][k]*w[n][k]
__global__ __launch_bounds__(256) void proj_gemm(
    const float* __restrict__ in, const float* __restrict__ w,
    float* __restrict__ P, int t0)
{
  __shared__ float As[8][132];
  __shared__ float Bs[8][132];
  const int tid = threadIdx.x;
  const int m0 = blockIdx.y << 7;
  const int n0 = blockIdx.x << 7;
  const int tm = tid >> 4, tn = tid & 15;
  const int lr = tid >> 1;
  const int lk = (tid & 1) << 2;
  const int mA = m0 + lr;
  const int bb = mA & 63;
  const int tg = t0 + (mA >> 6);
  const float* arow = in + ((size_t)bb << 18) + ((size_t)tg << 10) + lk;
  const float* brow = w + ((size_t)(n0 + lr) << 10) + lk;
  float acc[2][2][4][4] = {};
  for (int k0 = 0; k0 < 1024; k0 += 8) {
    float4 av = *(const float4*)(arow + k0);
    float4 bv = *(const float4*)(brow + k0);
    __syncthreads();
    As[lk + 0][lr] = av.x; As[lk + 1][lr] = av.y; As[lk + 2][lr] = av.z; As[lk + 3][lr] = av.w;
    Bs[lk + 0][lr] = bv.x; Bs[lk + 1][lr] = bv.y; Bs[lk + 2][lr] = bv.z; Bs[lk + 3][lr] = bv.w;
    __syncthreads();
#pragma unroll
    for (int kk = 0; kk < 8; ++kk) {
      float4 a0 = *(const float4*)&As[kk][tm << 2];
      float4 a1 = *(const float4*)&As[kk][(tm << 2) + 64];
      float4 b0 = *(const float4*)&Bs[kk][tn << 2];
      float4 b1 = *(const float4*)&Bs[kk][(tn << 2) + 64];
      const float* ap0 = (const float*)&a0;
      const float* ap1 = (const float*)&a1;
      const float* bp0 = (const float*)&b0;
      const float* bp1 = (const float*)&b1;
#pragma unroll
      for (int i = 0; i < 4; ++i)
#pragma unroll
        for (int j = 0; j < 4; ++j) {
          acc[0][0][i][j] = fmaf(ap0[i], bp0[j], acc[0][0][i][j]);
          acc[0][1][i][j] = fmaf(ap0[i], bp1[j], acc[0][1][i][j]);
          acc[1][0][i][j] = fmaf(ap1[i], bp0[j], acc[1][0][i][j]);
          acc[1][1][i][j] = fmaf(ap1[i], bp1[j], acc[1][1][i][j]);
        }
    }
  }
#pragma unroll
  for (int mi = 0; mi < 2; ++mi)
#pragma unroll
    for (int i = 0; i < 4; ++i) {
      int m = m0 + (mi << 6) + (tm << 2) + i;
      float* prow = P + ((size_t)m << 11) + n0 + (tn << 2);
      *(float4*)prow        = make_float4(acc[mi][0][i][0], acc[mi][0][i][1], acc[mi][0][i][2], acc[mi][0][i][3]);
      *(float4*)(prow + 64) = make_float4(acc[mi][1][i][0], acc[mi][1][i][1], acc[mi][1][i][2], acc[mi][1][i][3]);
    }
}

// ---- per-(tL,g) BN stats of P -> scale/shift (in_part = P*sc + sh)
__global__ __launch_bounds__(256) void bn_stats(
    const float* __restrict__ P, const float* __restrict__ iw, const float* __restrict__ ib,
    float* __restrict__ sc, float* __restrict__ sh)
{
  const int t = blockIdx.y;
  const int g = (blockIdx.x << 8) + threadIdx.x;
  const float* col = P + (((size_t)t << 6) << 11) + g;
  float s = 0.f, q = 0.f;
#pragma unroll 8
  for (int b = 0; b < 64; ++b) { float v = col[(size_t)b << 11]; s += v; q = fmaf(v, v, q); }
  float m = s * 0.015625f;
  float var = fmaf(-m, m, q * 0.015625f);
  float scale = iw[g] * rsqrtf(var + 1e-5f);
  sc[(t << 11) + g] = scale;
  sh[(t << 11) + g] = fmaf(-m, scale, ib[g]);
}

// ---- one recurrence step: split-bf16 MFMA GEMM + block-local BN + gate + h update.
// 64 blocks x 512 thr. Block: 16 u-cols (c0..c0+15) + 16 o-cols (+1024).
// Wave w: tile = w>>2 (0=u,1=o), kq = w&3 (k-quarter). lane&15 = frag row/col.
__global__ __launch_bounds__(512) void step_mfma(
    const unsigned short* __restrict__ hinh, const unsigned short* __restrict__ hinl,
    unsigned short* __restrict__ houth, unsigned short* __restrict__ houtl,
    const unsigned short* __restrict__ wbh, const unsigned short* __restrict__ wbl,
    const float* __restrict__ P, const float* __restrict__ sc, const float* __restrict__ sh,
    const float* __restrict__ hww, const float* __restrict__ hwb,
    const float* __restrict__ holdbase, long bstride,
    float* __restrict__ out, int t, int tL)
{
  __shared__ float part[8 * 16 * 68];   // [slot(=wave)][col][row pad 68]
  __shared__ float lout[64 * 20];
  const int tid = threadIdx.x;
  const int lane = tid & 63;
  const int w = tid >> 6;
  const int tile = w >> 2, kq = w & 3;
  const int c0 = blockIdx.x << 4;
  const int l15 = lane & 15;
  const int koct = (lane >> 4) << 3;

  // ---- epilogue operand prefetch (roles: b = lane, cs = w)
  const int b = lane, cs = w;
  const size_t prow = ((size_t)((tL << 6) + b)) << 11;
  const float pvu0 = P[prow + c0 + cs];
  const float pvu1 = P[prow + c0 + cs + 8];
  const float pvo0 = P[prow + c0 + cs + 1024];
  const float pvo1 = P[prow + c0 + cs + 1032];
  const float hold0 = holdbase[(size_t)b * bstride + c0 + cs];
  const float hold1 = holdbase[(size_t)b * bstride + c0 + cs + 8];

  // ---- MFMA phase: acc = Whi*hhi + Whi*hlo + Wlo*hhi
  const int gcol = c0 + l15 + (tile << 10);
  const int kbase = (kq << 8) + koct;
  const size_t woff = ((size_t)gcol << 10) + kbase;
  const size_t aoff = ((size_t)l15 << 10) + kbase;
  const unsigned short* bh = wbh + woff;
  const unsigned short* bl = wbl + woff;
  const unsigned short* ah = hinh + aoff;
  const unsigned short* al = hinl + aoff;
  f32x4 ac0 = {0.f, 0.f, 0.f, 0.f}, ac1 = ac0, ac2 = ac0, ac3 = ac0;
#pragma unroll
  for (int ks = 0; ks < 8; ++ks) {
    const int ko = ks << 5;
    bf16x8 bhv = *(const bf16x8*)(bh + ko);
    bf16x8 blv = *(const bf16x8*)(bl + ko);
    bf16x8 a0h = *(const bf16x8*)(ah + ko);
    bf16x8 a1h = *(const bf16x8*)(ah + ko + (16 << 10));
    bf16x8 a2h = *(const bf16x8*)(ah + ko + (32 << 10));
    bf16x8 a3h = *(const bf16x8*)(ah + ko + (48 << 10));
    bf16x8 a0l = *(const bf16x8*)(al + ko);
    bf16x8 a1l = *(const bf16x8*)(al + ko + (16 << 10));
    bf16x8 a2l = *(const bf16x8*)(al + ko + (32 << 10));
    bf16x8 a3l = *(const bf16x8*)(al + ko + (48 << 10));
    ac0 = __builtin_amdgcn_mfma_f32_16x16x32_bf16(a0h, bhv, ac0, 0, 0, 0);
    ac1 = __builtin_amdgcn_mfma_f32_16x16x32_bf16(a1h, bhv, ac1, 0, 0, 0);
    ac2 = __builtin_amdgcn_mfma_f32_16x16x32_bf16(a2h, bhv, ac2, 0, 0, 0);
    ac3 = __builtin_amdgcn_mfma_f32_16x16x32_bf16(a3h, bhv, ac3, 0, 0, 0);
    ac0 = __builtin_amdgcn_mfma_f32_16x16x32_bf16(a0l, bhv, ac0, 0, 0, 0);
    ac1 = __builtin_amdgcn_mfma_f32_16x16x32_bf16(a1l, bhv, ac1, 0, 0, 0);
    ac2 = __builtin_amdgcn_mfma_f32_16x16x32_bf16(a2l, bhv, ac2, 0, 0, 0);
    ac3 = __builtin_amdgcn_mfma_f32_16x16x32_bf16(a3l, bhv, ac3, 0, 0, 0);
    ac0 = __builtin_amdgcn_mfma_f32_16x16x32_bf16(a0h, blv, ac0, 0, 0, 0);
    ac1 = __builtin_amdgcn_mfma_f32_16x16x32_bf16(a1h, blv, ac1, 0, 0, 0);
    ac2 = __builtin_amdgcn_mfma_f32_16x16x32_bf16(a2h, blv, ac2, 0, 0, 0);
    ac3 = __builtin_amdgcn_mfma_f32_16x16x32_bf16(a3h, blv, ac3, 0, 0, 0);
  }
  {
    // C/D: col = lane&15, row = (lane>>4)*4 + reg (+ 16*mi)
    float* sp = part + (w * 16 + l15) * 68 + ((lane >> 4) << 2);
    *(f32x4*)(sp +  0) = ac0;
    *(f32x4*)(sp + 16) = ac1;
    *(f32x4*)(sp + 32) = ac2;
    *(f32x4*)(sp + 48) = ac3;
  }
  __syncthreads();

  // ---- BN + gates + h update; thread (b, cs) handles cols {cs, cs+8}
#pragma unroll
  for (int half = 0; half < 2; ++half) {
    const int csub = cs + (half << 3);
    const int gu = c0 + csub;
    float du = part[(0 * 16 + csub) * 68 + b] + part[(1 * 16 + csub) * 68 + b] +
               part[(2 * 16 + csub) * 68 + b] + part[(3 * 16 + csub) * 68 + b];
    float dv = part[(4 * 16 + csub) * 68 + b] + part[(5 * 16 + csub) * 68 + b] +
               part[(6 * 16 + csub) * 68 + b] + part[(7 * 16 + csub) * 68 + b];
    float su = wave_sum(du), qu = wave_sum(du * du);
    float so = wave_sum(dv), qo = wave_sum(dv * dv);
    float mu = su * 0.015625f, vu = fmaf(-mu, mu, qu * 0.015625f);
    float mo = so * 0.015625f, vo = fmaf(-mo, mo, qo * 0.015625f);
    float hpu = (du - mu) * (hww[gu] * rsqrtf(vu + 1e-5f)) + hwb[gu];
    float hpo = (dv - mo) * (hww[gu + 1024] * rsqrtf(vo + 1e-5f)) + hwb[gu + 1024];
    float inu = fmaf(half ? pvu1 : pvu0, sc[(tL << 11) + gu],        sh[(tL << 11) + gu]);
    float ino = fmaf(half ? pvo1 : pvo0, sc[(tL << 11) + gu + 1024], sh[(tL << 11) + gu + 1024]);
    float ug = 1.f / (1.f + expf(-(inu + hpu)));
    float og = fmaxf(ino + hpo, 0.f);
    float hold = half ? hold1 : hold0;
    lout[b * 20 + csub] = fmaf(ug, hold - og, og);   // ug*h + (1-ug)*og
  }
  __syncthreads();

  if (tid < 256) {   // coalesced final writes
    const int b2 = tid >> 2, q = tid & 3;
    float4 v = *(const float4*)&lout[b2 * 20 + (q << 2)];
    *(float4*)(out + (((size_t)(b2 << 8) + t) << 10) + c0 + (q << 2)) = v;
    ushort4 h4, l4;
    split2(v.x, h4.x, l4.x); split2(v.y, h4.y, l4.y);
    split2(v.z, h4.z, l4.z); split2(v.w, h4.w, l4.w);
    *(ushort4*)(houth + ((size_t)b2 << 10) + c0 + (q << 2)) = h4;
    *(ushort4*)(houtl + ((size_t)b2 << 10) + c0 + (q << 2)) = l4;
  }
}

extern "C" void kernel_launch(void* const* d_in, const int* in_sizes, int n_in,
                              void* d_out, int out_size, void* d_ws, size_t ws_size,
                              hipStream_t stream) {
  const float* x   = (const float*)d_in[0];
  const float* hx  = (const float*)d_in[1];
  const float* wih = (const float*)d_in[2];
  const float* whh = (const float*)d_in[3];
  // d_in[4], d_in[5] = b_ih, b_hh: cancelled exactly by batch-norm mean subtraction
  const float* biw = (const float*)d_in[6];
  const float* bib = (const float*)d_in[7];
  const float* bhw = (const float*)d_in[8];
  const float* bhb = (const float*)d_in[9];
  float* out = (float*)d_out;

  // ws floats: hA hi/lo + hB hi/lo (4 x 32768) | w hi/lo (2 x 1048576) | P TS*131072 | sc,sh TS*2048 each
  const size_t wsf = ws_size / 4;
  const size_t fixedf = 4 * 32768 + 2 * 1048576;
  int TS = 256;
  while (TS > 2) {
    size_t need = fixedf + (size_t)TS * (131072 + 4096);
    if (need <= wsf) break;
    TS >>= 1;
  }
  unsigned short* hAh = (unsigned short*)d_ws;
  unsigned short* hAl = hAh + 65536;
  unsigned short* hBh = hAl + 65536;
  unsigned short* hBl = hBh + 65536;
  unsigned short* wbh = hBl + 65536;
  unsigned short* wbl = wbh + 2097152;
  float* P  = (float*)d_ws + fixedf;
  float* sc = P + (size_t)TS * 131072;
  float* sh = sc + (size_t)TS * 2048;

  for (int layer = 0; layer < 2; ++layer) {
    const float* inp   = layer ? (const float*)out : x;
    const float* wih_l = wih + (size_t)layer * 2048 * 1024;
    const float* whh_l = whh + (size_t)layer * 2048 * 1024;
    const float* biw_l = biw + layer * 2048;
    const float* bib_l = bib + layer * 2048;
    const float* bhw_l = bhw + layer * 2048;
    const float* bhb_l = bhb + layer * 2048;
    const float* hx_l  = hx + (size_t)layer * 65536;

    wconv<<<dim3(1024), 256, 0, stream>>>(whh_l, wbh, wbl);
    hinit<<<dim3(32), 256, 0, stream>>>(hx_l, hAh, hAl);

    for (int t0 = 0; t0 < 256; t0 += TS) {
      proj_gemm<<<dim3(16, TS / 2), 256, 0, stream>>>(inp, wih_l, P, t0);
      bn_stats<<<dim3(8, TS), 256, 0, stream>>>(P, biw_l, bib_l, sc, sh);
      for (int t = t0; t < t0 + TS; ++t) {
        const unsigned short* hinh = (t & 1) ? hBh : hAh;
        const unsigned short* hinl = (t & 1) ? hBl : hAl;
        unsigned short* houth = (t & 1) ? hAh : hBh;
        unsigned short* houtl = (t & 1) ? hAl : hBl;
        const float* holdbase = (t == 0) ? hx_l : (const float*)(out + ((size_t)(t - 1) << 10));
        long bstride = (t == 0) ? 1024 : 262144;
        step_mfma<<<dim3(64), 512, 0, stream>>>(hinh, hinl, houth, houtl, wbh, wbl,
                                                P, sc, sh, bhw_l, bhb_l, holdbase, bstride,
                                                out, t, t - t0);
      }
    }
  }
}